// Round 1
// baseline (1049.034 us; speedup 1.0000x reference)
//
#include <hip/hip_runtime.h>
#include <math.h>

// MADDPG actor inference: obs-build + 39->64->64->5 MLP, B=1M items.
// v2: block-cooperative COALESCED staging. Each block owns 256 consecutive
// items (143,360 B). The per-item gather (stride-560B float4s = 64 cache
// lines per wave-load) is replaced by 3 dense float2 streaming phases over
// row-chunks {0-7, 8-15, 16-19}; fields are extracted from a padded LDS
// tile (58-float stride -> no pathological bank conflicts, float2-aligned).
// idx[] is wave-uniform so all row-in-chunk branches are scalar.
// Next chunk's global loads issue BEFORE previous chunk's extraction
// (issue-early/write-late) to hide HBM latency under LDS work.
// MLP compute identical (same FMA order) to the previous verified kernel.

#define NROW 20
#define NF   7
#define ITEM_F (NROW * NF)   // 140 floats per item
#define BLOCK 256
#define LSTF  58             // LDS floats per item (56 data + 2 pad)
#define LSTF2 29             // LDS float2 stride per item

typedef float v2 __attribute__((ext_vector_type(2)));

__device__ __forceinline__ void row_fma(v2 (&h)[32], float o,
                                        const float* __restrict__ wrow) {
    const v2* w = (const v2*)wrow;   // rows are 256B-aligned (64 floats)
    #pragma unroll
    for (int k = 0; k < 32; k++) {
        v2 ov; ov.x = o; ov.y = o;
        h[k] = __builtin_elementwise_fma(ov, w[k], h[k]);
    }
}

// Dense coalesced load of one row-chunk for this block's items.
// Flat f2-index q = k*256 + tid ; item i = q / F2PI ; slot v = q % F2PI.
// Consecutive lanes hit consecutive addresses within an item's chunk
// (F2PI*8 bytes contiguous), so a wave touches ~10-18 lines, not 64.
template<int F2PI, bool CLAMP>
__device__ __forceinline__ void stage_load(const float* __restrict__ gbase,
                                           int tid, int ilim, v2 (&st)[F2PI]) {
    constexpr int SI = 256 / F2PI;
    constexpr int SV = 256 % F2PI;
    int i = tid / F2PI;
    int v = tid - i * F2PI;
    #pragma unroll
    for (int k = 0; k < F2PI; k++) {
        int ic = CLAMP ? ((i < ilim) ? i : ilim) : i;
        st[k] = *(const v2*)(gbase + (long)ic * ITEM_F + 2 * v);
        i += SI; v += SV;
        if (v >= F2PI) { v -= F2PI; i += 1; }
    }
}

template<int F2PI>
__device__ __forceinline__ void stage_write(float* __restrict__ ldsf,
                                            int tid, const v2 (&st)[F2PI]) {
    constexpr int SI = 256 / F2PI;
    constexpr int SV = 256 % F2PI;
    v2* lf2 = (v2*)ldsf;
    int i = tid / F2PI;
    int v = tid - i * F2PI;
    #pragma unroll
    for (int k = 0; k < F2PI; k++) {
        lf2[i * LSTF2 + v] = st[k];
        i += SI; v += SV;
        if (v >= F2PI) { v -= F2PI; i += 1; }
    }
}

__device__ __forceinline__ void obst_extract(const float* __restrict__ myl,
                                             int base, float px, float py,
                                             float (&o)[5], int& any) {
    float q0 = myl[base + 0], q1 = myl[base + 1], q2 = myl[base + 2];
    float q3 = myl[base + 3], q4 = myl[base + 4];
    float dx = q0 - px, dy = q1 - py;
    bool  m  = sqrtf(dx*dx + dy*dy) < 0.15f;
    o[0] = m ? dx : 0.0f;
    o[1] = m ? dy : 0.0f;
    o[2] = m ? q2 : 0.0f;
    o[3] = m ? q3 : 0.0f;
    o[4] = m ? q4 : 0.0f;
    any  = __any(m);
}

__global__ __launch_bounds__(BLOCK, 2) void maddpg_kernel(
    const float* __restrict__ x,
    const float* __restrict__ W1, const float* __restrict__ b1,
    const float* __restrict__ W2, const float* __restrict__ b2,
    const float* __restrict__ W3, const float* __restrict__ b3,
    const int*   __restrict__ idx,
    float2*      __restrict__ out,
    int nitems)
{
    __shared__ float lds[BLOCK * LSTF];   // 59,392 B (<64 KiB)

    const int  tid  = threadIdx.x;
    const long blk0 = (long)blockIdx.x * BLOCK;
    const float* xblk = x + blk0 * ITEM_F;

    long rem  = (long)nitems - blk0;
    const bool full = (rem >= BLOCK);
    int  ilim = full ? (BLOCK - 1) : ((int)rem - 1);

    int sidx[8];
    #pragma unroll
    for (int t = 0; t < 8; t++) sidx[t] = idx[t];   // wave-uniform (s_load)

    float px, py, s2v, s3v, s4v;
    float mo[6];
    float oa[5][5];
    int   anyt[5];

    const float* myl = lds + tid * LSTF;

    // ---------------- chunk 0: rows 0..7 ----------------
    v2 st0[28];
    if (full) stage_load<28, false>(xblk + 0 * 56, tid, ilim, st0);
    else      stage_load<28, true >(xblk + 0 * 56, tid, ilim, st0);
    stage_write<28>(lds, tid, st0);
    __syncthreads();

    // issue chunk-1 loads early: overlap HBM latency with chunk-0 extraction
    v2 st1[28];
    if (full) stage_load<28, false>(xblk + 1 * 56, tid, ilim, st1);
    else      stage_load<28, true >(xblk + 1 * 56, tid, ilim, st1);

    // extract chunk 0
    px = myl[0]; py = myl[1]; s2v = myl[2]; s3v = myl[3]; s4v = myl[4];
    #pragma unroll
    for (int t = 0; t < 3; t++) {
        int r = sidx[t];                       // in [0,10)
        if ((r >> 3) == 0) {                   // uniform branch
            int base = (r & 7) * NF;
            float ax = myl[base + 0], ay = myl[base + 1];
            float bx = myl[base + 5], by = myl[base + 6];
            mo[2*t + 0] = bx + ax - px;
            mo[2*t + 1] = by + ay - py;
        }
    }
    __syncthreads();                           // all readers of chunk 0 done
    stage_write<28>(lds, tid, st1);
    __syncthreads();

    // issue chunk-2 loads early
    v2 st2[14];
    if (full) stage_load<14, false>(xblk + 2 * 56, tid, ilim, st2);
    else      stage_load<14, true >(xblk + 2 * 56, tid, ilim, st2);

    // extract chunk 1 (rows 8..15)
    #pragma unroll
    for (int t = 0; t < 3; t++) {
        int r = sidx[t];
        if ((r >> 3) == 1) {
            int base = (r & 7) * NF;
            float ax = myl[base + 0], ay = myl[base + 1];
            float bx = myl[base + 5], by = myl[base + 6];
            mo[2*t + 0] = bx + ax - px;
            mo[2*t + 1] = by + ay - py;
        }
    }
    #pragma unroll
    for (int t = 0; t < 5; t++) {
        int r = sidx[3 + t] + NROW/2;          // in [10,20)
        if ((r >> 3) == 1)
            obst_extract(myl, (r & 7) * NF, px, py, oa[t], anyt[t]);
    }
    __syncthreads();
    stage_write<14>(lds, tid, st2);
    __syncthreads();

    // extract chunk 2 (rows 16..19)
    #pragma unroll
    for (int t = 0; t < 5; t++) {
        int r = sidx[3 + t] + NROW/2;
        if ((r >> 3) == 2)
            obst_extract(myl, (r & 7) * NF, px, py, oa[t], anyt[t]);
    }

    // ---------------- layer 1: 39 -> 64 (rows 7,10,13 are zero) -------------
    v2 h[32];
    const v2* b1v = (const v2*)b1;
    #pragma unroll
    for (int k = 0; k < 32; k++) h[k] = b1v[k];

    row_fma(h, px,  W1 + 0*64);
    row_fma(h, py,  W1 + 1*64);
    row_fma(h, s2v, W1 + 2*64);
    row_fma(h, s3v, W1 + 3*64);
    row_fma(h, s4v, W1 + 4*64);
    #pragma unroll
    for (int t = 0; t < 3; t++) {
        row_fma(h, mo[2*t + 0], W1 + (5 + 3*t)*64);
        row_fma(h, mo[2*t + 1], W1 + (6 + 3*t)*64);
    }
    #pragma unroll
    for (int t = 0; t < 5; t++) {
        if (anyt[t]) {                  // uniform branch: skip all-zero block
            #pragma unroll
            for (int j = 0; j < 5; j++)
                row_fma(h, oa[t][j], W1 + (14 + 5*t + j)*64);
        }
    }

    // relu
    v2 a[32];
    #pragma unroll
    for (int k = 0; k < 32; k++) {
        a[k].x = fmaxf(h[k].x, 0.0f);
        a[k].y = fmaxf(h[k].y, 0.0f);
    }

    // ---------------- layer 2: 64 -> 64 ----------------
    const v2* b2v = (const v2*)b2;
    #pragma unroll
    for (int k = 0; k < 32; k++) h[k] = b2v[k];
    #pragma unroll
    for (int i = 0; i < 64; i++) {
        float o = (i & 1) ? a[i >> 1].y : a[i >> 1].x;
        row_fma(h, o, W2 + i*64);
    }
    #pragma unroll
    for (int k = 0; k < 32; k++) {
        a[k].x = fmaxf(h[k].x, 0.0f);
        a[k].y = fmaxf(h[k].y, 0.0f);
    }

    // ---------------- layer 3: only cols 1..4 needed ----------------
    v2 rA; rA.x = b3[1]; rA.y = b3[2];
    v2 rB; rB.x = b3[3]; rB.y = b3[4];
    #pragma unroll
    for (int i = 0; i < 64; i++) {
        float o = (i & 1) ? a[i >> 1].y : a[i >> 1].x;
        const float* w = W3 + i*5;
        v2 ov; ov.x = o; ov.y = o;
        v2 wA; wA.x = w[1]; wA.y = w[2];
        v2 wB; wB.x = w[3]; wB.y = w[4];
        rA = __builtin_elementwise_fma(ov, wA, rA);
        rB = __builtin_elementwise_fma(ov, wB, rB);
    }

    float v0 = (rA.x - rA.y) * 0.1f;
    float v1 = (rB.x - rB.y) * 0.1f;
    if (fabsf(v0) > 1.0f) v0 = copysignf(2.0f, v0);
    if (fabsf(v1) > 1.0f) v1 = copysignf(2.0f, v1);

    if (blk0 + tid < (long)nitems)
        out[blk0 + tid] = make_float2(v0, v1);
}

extern "C" void kernel_launch(void* const* d_in, const int* in_sizes, int n_in,
                              void* d_out, int out_size, void* d_ws, size_t ws_size,
                              hipStream_t stream) {
    const float* x  = (const float*)d_in[0];
    const float* W1 = (const float*)d_in[1];
    const float* b1 = (const float*)d_in[2];
    const float* W2 = (const float*)d_in[3];
    const float* b2 = (const float*)d_in[4];
    const float* W3 = (const float*)d_in[5];
    const float* b3 = (const float*)d_in[6];
    const int*   idx = (const int*)d_in[7];
    float2* out = (float2*)d_out;

    int nitems = in_sizes[0] / ITEM_F;   // 1048576
    int grid = (nitems + BLOCK - 1) / BLOCK;
    maddpg_kernel<<<grid, BLOCK, 0, stream>>>(x, W1, b1, W2, b2, W3, b3, idx,
                                              out, nitems);
}